// Round 1
// 125.970 us; speedup vs baseline: 1.0353x; 1.0353x over previous
//
#include <hip/hip_runtime.h>

#define BATCH 1024
#define N_IN 1024
#define TOTAL 18432   // 1024 + 8*2048 + 1024
#define BLOCK 1024
#define NNEUR 17408   // 8*2048 + 1024

__device__ __forceinline__ float fast_tanh(float x) {
    // tanh(x) = 1 - 2/(1+exp(2x)) ; exact at saturation, ~1e-7 rel error
    float e = __expf(2.0f * x);
    return 1.0f - 2.0f / (1.0f + e);
}

// ---------- Preprocessing: transpose + bank-balancing slot assignment ----------
// Main kernel gathers vals[idx] as float2 (8B): LDS bank-pair = idx mod 16.
// For slot s (s = 4g+comp) and lane l = neuron&63, we TARGET residue (s+l)&15.
// If every lane delivered its target, each slot would see each residue exactly
// 4x across the wave -> near-conflict-free. Each neuron greedily matches its 32
// indices (sum is commutative -> any per-neuron permutation is correct) to the
// two slots targeting each residue; leftovers fill remaining free slots.
// Per-thread dynamic-indexed arrays live in LDS (rule: runtime-indexed register
// arrays spill to scratch).
#define PREP_T 256
__global__ __launch_bounds__(PREP_T) void prep_kernel(const int4* __restrict__ cidx4,
                                                      int4* __restrict__ idxT) {
    __shared__ int out_s[32 * PREP_T];    // [slot][tid] assigned index value
    __shared__ int left_s[32 * PREP_T];   // [i][tid] leftover queue
    const int m = blockIdx.x * PREP_T + threadIdx.x;
    const int tid = threadIdx.x;
    if (m >= NNEUR) return;

    const int layer = min(m >> 11, 8);
    const int nloc  = m - (layer << 11);
    const int sz    = (layer == 8) ? 1024 : 2048;
    const int ptr   = layer << 11;
    const int lane  = nloc & 63;
    // lane-parity swap of first/second preferred slot evens out the matched
    // probability between low (s<16) and high (s>=16) slots.
    const int hiFirst = (lane & 1) << 4;

    const int4* src = cidx4 + (size_t)m * 8;
    int4 v[8];
    #pragma unroll
    for (int g = 0; g < 8; ++g) v[g] = src[g];

    unsigned slotFree = 0xFFFFFFFFu;
    int nleft = 0;
    #pragma unroll
    for (int g = 0; g < 8; ++g) {
        int comp[4] = {v[g].x, v[g].y, v[g].z, v[g].w};
        #pragma unroll
        for (int c = 0; c < 4; ++c) {
            const int id = comp[c];
            const int s1 = ((id & 15) - lane) & 15;   // low slot targeting this residue
            const int sA = s1 + hiFirst;
            const int sB = s1 + (hiFirst ^ 16);
            if (slotFree >> sA & 1u) {
                out_s[sA * PREP_T + tid] = id;
                slotFree &= ~(1u << sA);
            } else if (slotFree >> sB & 1u) {
                out_s[sB * PREP_T + tid] = id;
                slotFree &= ~(1u << sB);
            } else {
                left_s[nleft * PREP_T + tid] = id;
                ++nleft;
            }
        }
    }
    // fill leftovers into the remaining free slots (counts match exactly)
    unsigned f = slotFree;
    for (int i = 0; i < nleft; ++i) {
        const int s = __builtin_ctz(f);
        f &= f - 1;
        out_s[s * PREP_T + tid] = left_s[i * PREP_T + tid];
    }
    // write transposed, coalesced: group g owns slots 4g..4g+3
    int4* dst = idxT + (size_t)ptr * 8;
    #pragma unroll
    for (int g = 0; g < 8; ++g) {
        int4 o;
        o.x = out_s[(4 * g + 0) * PREP_T + tid];
        o.y = out_s[(4 * g + 1) * PREP_T + tid];
        o.z = out_s[(4 * g + 2) * PREP_T + tid];
        o.w = out_s[(4 * g + 3) * PREP_T + tid];
        dst[(size_t)g * sz + nloc] = o;
    }
}

// ---------- Main kernel, transposed-index path (unchanged) ----------
__global__ __launch_bounds__(BLOCK) void net_kernel_t(
    const float* __restrict__ X,
    const float* __restrict__ wptr,
    const int4* __restrict__ idxT,
    float* __restrict__ out)
{
    __shared__ float2 vals[TOTAL];   // 144 KB, rows (A,B) interleaved
    const int rowA = blockIdx.x * 2;
    const float w = wptr[0];
    const int t = threadIdx.x;

    {
        const float4* xa = reinterpret_cast<const float4*>(X + (size_t)rowA * N_IN);
        const float4* xb = reinterpret_cast<const float4*>(X + (size_t)(rowA + 1) * N_IN);
        for (int i = t; i < N_IN / 4; i += BLOCK) {
            float4 a = xa[i], b = xb[i];
            vals[4 * i + 0] = make_float2(a.x, b.x);
            vals[4 * i + 1] = make_float2(a.y, b.y);
            vals[4 * i + 2] = make_float2(a.z, b.z);
            vals[4 * i + 3] = make_float2(a.w, b.w);
        }
    }
    __syncthreads();

    int off = N_IN;
    const int4* L = idxT;
    #pragma unroll
    for (int li = 0; li < 9; ++li) {
        const int sz = (li == 8) ? 1024 : 2048;
        if (sz == 2048) {
            // two neurons per thread, interleaved for ILP
            const int n0 = t, n1 = t + 1024;
            float a0x = 0.f, a0y = 0.f, a1x = 0.f, a1y = 0.f;
            #pragma unroll
            for (int g = 0; g < 8; ++g) {
                int4 i0 = L[(size_t)g * 2048 + n0];
                int4 i1 = L[(size_t)g * 2048 + n1];
                float2 p = vals[i0.x], q = vals[i0.y], u = vals[i0.z], s = vals[i0.w];
                a0x += (p.x + q.x) + (u.x + s.x);
                a0y += (p.y + q.y) + (u.y + s.y);
                p = vals[i1.x]; q = vals[i1.y]; u = vals[i1.z]; s = vals[i1.w];
                a1x += (p.x + q.x) + (u.x + s.x);
                a1y += (p.y + q.y) + (u.y + s.y);
            }
            vals[off + n0] = make_float2(fast_tanh(w * a0x), fast_tanh(w * a0y));
            vals[off + n1] = make_float2(fast_tanh(w * a1x), fast_tanh(w * a1y));
        } else {
            const int n0 = t;
            float a0x = 0.f, a0y = 0.f;
            #pragma unroll
            for (int g = 0; g < 8; ++g) {
                int4 i0 = L[(size_t)g * 1024 + n0];
                float2 p = vals[i0.x], q = vals[i0.y], u = vals[i0.z], s = vals[i0.w];
                a0x += (p.x + q.x) + (u.x + s.x);
                a0y += (p.y + q.y) + (u.y + s.y);
            }
            vals[off + n0] = make_float2(fast_tanh(w * a0x), fast_tanh(w * a0y));
        }
        __syncthreads();
        off += sz;
        L += (size_t)sz * 8;
    }

    {
        float* oA = out + (size_t)rowA * 1024;
        float* oB = out + (size_t)(rowA + 1) * 1024;
        const float2* src = vals + (TOTAL - 1024);
        for (int i = t; i < 1024; i += BLOCK) {
            float2 v = src[i];
            oA[i] = v.x;
            oB[i] = v.y;
        }
    }
}

// ---------- Fallback (ws too small): unchanged ----------
__global__ __launch_bounds__(BLOCK) void net_kernel_f(
    const float* __restrict__ X,
    const float* __restrict__ wptr,
    const int* __restrict__ cidx,
    float* __restrict__ out)
{
    __shared__ float2 vals[TOTAL];
    const int rowA = blockIdx.x * 2;
    const float w = wptr[0];
    const int t = threadIdx.x;
    {
        const float4* xa = reinterpret_cast<const float4*>(X + (size_t)rowA * N_IN);
        const float4* xb = reinterpret_cast<const float4*>(X + (size_t)(rowA + 1) * N_IN);
        for (int i = t; i < N_IN / 4; i += BLOCK) {
            float4 a = xa[i], b = xb[i];
            vals[4 * i + 0] = make_float2(a.x, b.x);
            vals[4 * i + 1] = make_float2(a.y, b.y);
            vals[4 * i + 2] = make_float2(a.z, b.z);
            vals[4 * i + 3] = make_float2(a.w, b.w);
        }
    }
    __syncthreads();
    int off = N_IN, ptr = 0;
    #pragma unroll
    for (int li = 0; li < 9; ++li) {
        const int sz = (li == 8) ? 1024 : 2048;
        for (int n = t; n < sz; n += BLOCK) {
            const int4* ip = reinterpret_cast<const int4*>(cidx + (size_t)(ptr + n) * 32);
            float sx = 0.f, sy = 0.f;
            #pragma unroll
            for (int j = 0; j < 8; ++j) {
                const int4 v = ip[j];
                float2 a = vals[v.x], b = vals[v.y], c = vals[v.z], d = vals[v.w];
                sx += (a.x + b.x) + (c.x + d.x);
                sy += (a.y + b.y) + (c.y + d.y);
            }
            vals[off + n] = make_float2(fast_tanh(w * sx), fast_tanh(w * sy));
        }
        __syncthreads();
        off += sz;
        ptr += sz;
    }
    {
        float* oA = out + (size_t)rowA * 1024;
        float* oB = out + (size_t)(rowA + 1) * 1024;
        const float2* src = vals + (TOTAL - 1024);
        for (int i = t; i < 1024; i += BLOCK) {
            float2 v = src[i];
            oA[i] = v.x;
            oB[i] = v.y;
        }
    }
}

extern "C" void kernel_launch(void* const* d_in, const int* in_sizes, int n_in,
                              void* d_out, int out_size, void* d_ws, size_t ws_size,
                              hipStream_t stream)
{
    const float* X    = (const float*)d_in[0];
    const float* w    = (const float*)d_in[1];
    const int*   cidx = (const int*)d_in[2];
    float* out = (float*)d_out;

    const size_t need = (size_t)NNEUR * 32 * sizeof(int);   // 2.23 MB
    if (ws_size >= need) {
        int4* idxT = (int4*)d_ws;
        hipLaunchKernelGGL(prep_kernel, dim3((NNEUR + PREP_T - 1) / PREP_T), dim3(PREP_T), 0, stream,
                           (const int4*)cidx, idxT);
        hipLaunchKernelGGL(net_kernel_t, dim3(BATCH / 2), dim3(BLOCK), 0, stream,
                           X, w, idxT, out);
    } else {
        hipLaunchKernelGGL(net_kernel_f, dim3(BATCH / 2), dim3(BLOCK), 0, stream,
                           X, w, cidx, out);
    }
}